// Round 2
// baseline (288.420 us; speedup 1.0000x reference)
//
#include <hip/hip_runtime.h>

typedef unsigned short u16;
typedef unsigned int u32;

#define N_NODES 100000
#define N_EDGES 50000
#define C 128
#define G_GEMM 1563               // 1563 blocks * 4 waves = 6252 tiles >= 6250
#define NCNT (N_EDGES + N_NODES)  // 150000 combined count/offset table
#define SCAN_BLOCKS ((NCNT + 1023) >> 10)  // 147

static __device__ __forceinline__ float bf2f(u16 h) {
    u32 u = ((u32)h) << 16;
    float f;
    __builtin_memcpy(&f, &u, 4);
    return f;
}

static __device__ __forceinline__ u16 f2bf(float f) {
    u32 u;
    __builtin_memcpy(&u, &f, 4);
    return (u16)((u + 0x7fffu + ((u >> 16) & 1u)) >> 16);  // RNE
}

typedef short s16x8 __attribute__((ext_vector_type(8)));
typedef float f32x4 __attribute__((ext_vector_type(4)));

// ---------------- W transpose -> bf16: Wt[oc][k] = bf16(W[k][oc]) ----------
__global__ void transpose_w(const float* __restrict__ W, u16* __restrict__ Wt) {
    int idx = blockIdx.x * 256 + threadIdx.x;  // 16384 total
    int k = idx >> 7, oc = idx & 127;
    Wt[oc * 128 + k] = f2bf(W[k * 128 + oc]);
}

// ---------------- fused: MFMA GEMM (blocks < G_GEMM) + histogram ----------
// GEMM first (round-1 lesson: build-first queues GEMM behind the atomic storm).
// Histogram replaces the linked-list build: 1M atomicAdd into a 600KB
// L2-resident table, NO scattered payload writes (kills the 64MB WRITE_SIZE).
// GEMM: xw[n][oc] = x[n][:] . W[:][oc], bf16 out. One wave per 16-row tile;
// A[m=lane&15][k=quad*8+j]; D col=lane&15, row=quad*4+reg (verified m89/m91).
__global__ __launch_bounds__(256) void fused_gemm_hist(
    const float* __restrict__ x, const u16* __restrict__ Wt,
    u16* __restrict__ xw,
    const int* __restrict__ ni, const int* __restrict__ ei,
    u32* __restrict__ cnt, int nnz) {
    if ((int)blockIdx.x < G_GEMM) {
        int wave = threadIdx.x >> 6;
        int tile = blockIdx.x * 4 + wave;
        if (tile >= 6250) return;
        int lane = threadIdx.x & 63;
        int m = lane & 15;
        int quad = lane >> 4;
        int row0 = tile * 16;

        f32x4 acc[8];
#pragma unroll
        for (int nt = 0; nt < 8; ++nt) acc[nt] = (f32x4){0.f, 0.f, 0.f, 0.f};

        for (int k0 = 0; k0 < 128; k0 += 32) {
            int kb = k0 + quad * 8;
            const float* p = x + (size_t)(row0 + m) * C + kb;
            float4 v0 = *(const float4*)p;
            float4 v1 = *(const float4*)(p + 4);
            union { uint4 u; s16x8 v; } a;
            a.u.x = (u32)f2bf(v0.x) | ((u32)f2bf(v0.y) << 16);
            a.u.y = (u32)f2bf(v0.z) | ((u32)f2bf(v0.w) << 16);
            a.u.z = (u32)f2bf(v1.x) | ((u32)f2bf(v1.y) << 16);
            a.u.w = (u32)f2bf(v1.z) | ((u32)f2bf(v1.w) << 16);
#pragma unroll
            for (int nt = 0; nt < 8; ++nt) {
                union { uint4 u; s16x8 v; } b;
                b.u = *(const uint4*)(Wt + (size_t)(nt * 16 + m) * C + kb);
                acc[nt] = __builtin_amdgcn_mfma_f32_16x16x32_bf16(a.v, b.v, acc[nt], 0, 0, 0);
            }
        }

#pragma unroll
        for (int nt = 0; nt < 8; ++nt) {
#pragma unroll
            for (int r = 0; r < 4; ++r) {
                int row = row0 + quad * 4 + r;
                xw[(size_t)row * C + nt * 16 + m] = f2bf(acc[nt][r]);
            }
        }
    } else {
        int i = (blockIdx.x - G_GEMM) * 256 + threadIdx.x;
        if (i < nnz) {
            atomicAdd(&cnt[ei[i]], 1u);
            atomicAdd(&cnt[N_EDGES + ni[i]], 1u);
        }
    }
}

// ---------------- scan stage A: per-block exclusive scan of cnt -----------
// 1024 elems/block (256 thr x 4). Writes block-local exclusive offsets to
// off[] and the block total to bsum[blk]. Block prefix is added on the fly
// by consumers (off_final[i] = off[i] + bsum[i>>10]) — saves a 3rd pass.
__global__ __launch_bounds__(256) void scan_a(const u32* __restrict__ cnt,
                                              u32* __restrict__ off,
                                              u32* __restrict__ bsum) {
    __shared__ u32 wsum[4];
    int tid = threadIdx.x;
    int base = blockIdx.x * 1024 + tid * 4;
    u32 v0 = 0, v1 = 0, v2 = 0, v3 = 0;
    if (base + 3 < NCNT) {
        uint4 v = *(const uint4*)(cnt + base);
        v0 = v.x; v1 = v.y; v2 = v.z; v3 = v.w;
    } else {
        if (base + 0 < NCNT) v0 = cnt[base + 0];
        if (base + 1 < NCNT) v1 = cnt[base + 1];
        if (base + 2 < NCNT) v2 = cnt[base + 2];
        if (base + 3 < NCNT) v3 = cnt[base + 3];
    }
    u32 s = v0 + v1 + v2 + v3;
    int lane = tid & 63, wv = tid >> 6;
    u32 x = s;
    for (int d = 1; d < 64; d <<= 1) {
        u32 y = __shfl_up(x, (unsigned)d);
        if (lane >= d) x += y;
    }
    if (lane == 63) wsum[wv] = x;
    __syncthreads();
    u32 wo = 0;
    for (int w = 0; w < 4; ++w) wo += (w < wv) ? wsum[w] : 0u;
    u32 ex = wo + x - s;
    if (base + 0 < NCNT) off[base + 0] = ex;
    if (base + 1 < NCNT) off[base + 1] = ex + v0;
    if (base + 2 < NCNT) off[base + 2] = ex + v0 + v1;
    if (base + 3 < NCNT) off[base + 3] = ex + v0 + v1 + v2;
    if (tid == 255) bsum[blockIdx.x] = wo + x;  // block total
}

// ---------------- scan stage B: exclusive scan of the 147 block sums ------
__global__ __launch_bounds__(256) void scan_b(u32* __restrict__ bsum) {
    __shared__ u32 wsum[4];
    int tid = threadIdx.x;
    u32 s = (tid < SCAN_BLOCKS) ? bsum[tid] : 0u;
    int lane = tid & 63, wv = tid >> 6;
    u32 x = s;
    for (int d = 1; d < 64; d <<= 1) {
        u32 y = __shfl_up(x, (unsigned)d);
        if (lane >= d) x += y;
    }
    if (lane == 63) wsum[wv] = x;
    __syncthreads();
    u32 wo = 0;
    for (int w = 0; w < 4; ++w) wo += (w < wv) ? wsum[w] : 0u;
    if (tid < SCAN_BLOCKS) bsum[tid] = wo + x - s;  // exclusive prefix
}

// ---------------- scatter: counting-sort incidences into CSR --------------
// Edge entries land in csrE[0..nnz) (value = node), node entries in
// csrN[0..nnz) (value = edge; combined-space position minus nnz).
// After this kernel off[j] has advanced by cnt[j], so consumers recover
// start = off[j] + bsum[j>>10] - cnt[j].
__global__ __launch_bounds__(256) void scatter_k(const int* __restrict__ ni,
                                                 const int* __restrict__ ei,
                                                 u32* __restrict__ off,
                                                 const u32* __restrict__ bsum,
                                                 u32* __restrict__ csrE,
                                                 u32* __restrict__ csrN, int nnz) {
    int i = blockIdx.x * 256 + threadIdx.x;
    if (i >= nnz) return;
    int n = ni[i], e = ei[i];
    u32 p = atomicAdd(&off[e], 1u) + bsum[e >> 10];
    csrE[p] = (u32)n;
    int j = N_EDGES + n;
    u32 q = atomicAdd(&off[j], 1u) + bsum[j >> 10];
    csrN[q - (u32)nnz] = (u32)e;
}

// ---------------- edge gather over CSR: 1 edge per wave -------------------
// ef[e] = bf16(B^-1_e * sum xw[nodes of e]); lane owns channels {2l,2l+1}.
// One coalesced 64-wide index load + shfl broadcast -> row loads are
// address-independent; 4-deep manual unroll keeps 4 row loads in flight.
__global__ __launch_bounds__(256) void edge_gather_k(const u16* __restrict__ xw,
                                                     const u32* __restrict__ cnt,
                                                     const u32* __restrict__ off,
                                                     const u32* __restrict__ bsum,
                                                     const u32* __restrict__ csrE,
                                                     u16* __restrict__ ef) {
    int e = blockIdx.x * 4 + (threadIdx.x >> 6);
    if (e >= N_EDGES) return;
    int lane = threadIdx.x & 63;
    u32 deg = cnt[e];
    u32 end = off[e] + bsum[e >> 10];   // post-scatter off = local start + deg
    u32 start = end - deg;
    float ax = 0.f, ay = 0.f;
    for (u32 base = 0; base < deg; base += 64) {
        int m = (int)min(64u, deg - base);
        int myidx = (lane < m) ? (int)csrE[start + base + lane] : 0;
        int t = 0;
        for (; t + 3 < m; t += 4) {
            int r0 = __shfl(myidx, t);
            int r1 = __shfl(myidx, t + 1);
            int r2 = __shfl(myidx, t + 2);
            int r3 = __shfl(myidx, t + 3);
            u32 u0 = ((const u32*)(xw + (size_t)r0 * C))[lane];
            u32 u1 = ((const u32*)(xw + (size_t)r1 * C))[lane];
            u32 u2 = ((const u32*)(xw + (size_t)r2 * C))[lane];
            u32 u3 = ((const u32*)(xw + (size_t)r3 * C))[lane];
            ax += bf2f((u16)(u0 & 0xffffu)) + bf2f((u16)(u1 & 0xffffu)) +
                  bf2f((u16)(u2 & 0xffffu)) + bf2f((u16)(u3 & 0xffffu));
            ay += bf2f((u16)(u0 >> 16)) + bf2f((u16)(u1 >> 16)) +
                  bf2f((u16)(u2 >> 16)) + bf2f((u16)(u3 >> 16));
        }
        for (; t < m; ++t) {
            int r = __shfl(myidx, t);
            u32 u = ((const u32*)(xw + (size_t)r * C))[lane];
            ax += bf2f((u16)(u & 0xffffu));
            ay += bf2f((u16)(u >> 16));
        }
    }
    float sc = deg ? 1.f / (float)deg : 0.f;
    ((u32*)(ef + (size_t)e * C))[lane] =
        (u32)f2bf(ax * sc) | ((u32)f2bf(ay * sc) << 16);
}

// ---------------- node gather over CSR: 1 node per wave -------------------
// out[v] = f32( D^-1_v * sum ef[edges of v] + b )
__global__ __launch_bounds__(256) void node_gather_k(const u16* __restrict__ ef,
                                                     const u32* __restrict__ cnt,
                                                     const u32* __restrict__ off,
                                                     const u32* __restrict__ bsum,
                                                     const u32* __restrict__ csrN,
                                                     const float* __restrict__ bias,
                                                     float* __restrict__ out, int nnz) {
    int v = blockIdx.x * 4 + (threadIdx.x >> 6);
    if (v >= N_NODES) return;
    int lane = threadIdx.x & 63;
    int j = N_EDGES + v;
    u32 deg = cnt[j];
    u32 end = off[j] + bsum[j >> 10];
    u32 start = end - deg - (u32)nnz;   // csrN-local base
    float ax = 0.f, ay = 0.f;
    for (u32 base = 0; base < deg; base += 64) {
        int m = (int)min(64u, deg - base);
        int myidx = (lane < m) ? (int)csrN[start + base + lane] : 0;
        int t = 0;
        for (; t + 3 < m; t += 4) {
            int r0 = __shfl(myidx, t);
            int r1 = __shfl(myidx, t + 1);
            int r2 = __shfl(myidx, t + 2);
            int r3 = __shfl(myidx, t + 3);
            u32 u0 = ((const u32*)(ef + (size_t)r0 * C))[lane];
            u32 u1 = ((const u32*)(ef + (size_t)r1 * C))[lane];
            u32 u2 = ((const u32*)(ef + (size_t)r2 * C))[lane];
            u32 u3 = ((const u32*)(ef + (size_t)r3 * C))[lane];
            ax += bf2f((u16)(u0 & 0xffffu)) + bf2f((u16)(u1 & 0xffffu)) +
                  bf2f((u16)(u2 & 0xffffu)) + bf2f((u16)(u3 & 0xffffu));
            ay += bf2f((u16)(u0 >> 16)) + bf2f((u16)(u1 >> 16)) +
                  bf2f((u16)(u2 >> 16)) + bf2f((u16)(u3 >> 16));
        }
        for (; t < m; ++t) {
            int r = __shfl(myidx, t);
            u32 u = ((const u32*)(ef + (size_t)r * C))[lane];
            ax += bf2f((u16)(u & 0xffffu));
            ay += bf2f((u16)(u >> 16));
        }
    }
    float b0 = bias[2 * lane], b1 = bias[2 * lane + 1];
    float sc = deg ? 1.f / (float)deg : 0.f;
    float2 r;
    r.x = ax * sc + b0;
    r.y = ay * sc + b1;
    ((float2*)(out + (size_t)v * C))[lane] = r;
}

extern "C" void kernel_launch(void* const* d_in, const int* in_sizes, int n_in,
                              void* d_out, int out_size, void* d_ws, size_t ws_size,
                              hipStream_t stream) {
    const float* x = (const float*)d_in[0];     // [N_NODES,128] f32
    const int* node_idx = (const int*)d_in[1];  // [2, NNZ] row-major int32
    const int nnz = in_sizes[1] / 2;
    const int* edge_idx = node_idx + nnz;
    const float* W = (const float*)d_in[2];     // [128,128] f32
    const float* bias = (const float*)d_in[3];  // [128] f32
    float* out = (float*)d_out;                 // [N_NODES,128] f32

    // workspace layout (~16.1 MB)
    u16* Wt = (u16*)d_ws;                           // 16384 u16 (32 KB)
    u16* ef = Wt + 16384;                           // 6.4M u16 (12.8 MB)
    u32* cnt = (u32*)(ef + (size_t)N_EDGES * C);    // 150000 u32 (600 KB)
    u32* off = cnt + NCNT;                          // 150000 u32 (600 KB)
    u32* bsum = off + NCNT;                         // 147 u32 (pad 256)
    u32* csrN = bsum + 256;                         // nnz u32 (2 MB)

    // d_out (51.2 MB f32) doubles as scratch:
    //   [0, 25.6 MB):      xw bf16 — consumed by edge_gather
    //   [25.6, 27.6 MB):   csrE    — consumed by edge_gather
    // node_gather then overwrites the whole buffer with the f32 output.
    u16* xw = (u16*)d_out;
    u32* csrE = (u32*)((char*)d_out + (size_t)N_NODES * C * 2);

    int nBuild = (nnz + 255) / 256;

    hipMemsetAsync(cnt, 0, (size_t)NCNT * 4, stream);
    transpose_w<<<64, 256, 0, stream>>>(W, Wt);
    fused_gemm_hist<<<G_GEMM + nBuild, 256, 0, stream>>>(
        x, Wt, xw, node_idx, edge_idx, cnt, nnz);
    scan_a<<<SCAN_BLOCKS, 256, 0, stream>>>(cnt, off, bsum);
    scan_b<<<1, 256, 0, stream>>>(bsum);
    scatter_k<<<nBuild, 256, 0, stream>>>(node_idx, edge_idx, off, bsum, csrE, csrN, nnz);
    // 1 edge/node per wave, 4 waves per block
    edge_gather_k<<<(N_EDGES + 3) / 4, 256, 0, stream>>>(xw, cnt, off, bsum, csrE, ef);
    node_gather_k<<<(N_NODES + 3) / 4, 256, 0, stream>>>(ef, cnt, off, bsum, csrN, bias, out, nnz);
}

// Round 4
// 255.813 us; speedup vs baseline: 1.1275x; 1.1275x over previous
//
#include <hip/hip_runtime.h>

typedef unsigned short u16;
typedef unsigned int u32;

#define N_NODES 100000
#define N_EDGES 50000
#define C 128
#define G_GEMM 1563               // 1563 blocks * 4 waves = 6252 tiles >= 6250
#define NCNT (N_EDGES + N_NODES)  // 150000 combined key space (edges then nodes)
#define NBIN 8                    // XCD-replicated counter copies
#define SCAN_BLOCKS ((NCNT + 1023) >> 10)  // 147

static __device__ __forceinline__ float bf2f(u16 h) {
    u32 u = ((u32)h) << 16;
    float f;
    __builtin_memcpy(&f, &u, 4);
    return f;
}

static __device__ __forceinline__ u16 f2bf(float f) {
    u32 u;
    __builtin_memcpy(&u, &f, 4);
    return (u16)((u + 0x7fffu + ((u >> 16) & 1u)) >> 16);  // RNE
}

typedef short s16x8 __attribute__((ext_vector_type(8)));
typedef float f32x4 __attribute__((ext_vector_type(4)));

// ---------------- W transpose -> bf16: Wt[oc][k] = bf16(W[k][oc]) ----------
__global__ void transpose_w(const float* __restrict__ W, u16* __restrict__ Wt) {
    int idx = blockIdx.x * 256 + threadIdx.x;  // 16384 total
    int k = idx >> 7, oc = idx & 127;
    Wt[oc * 128 + k] = f2bf(W[k * 128 + oc]);
}

// ---------------- GEMM standalone (attribution round) ---------------------
// xw[n][oc] = x[n][:] . W[:][oc], bf16 out. One wave per 16-row tile;
// A[m=lane&15][k=quad*8+j]; D col=lane&15, row=quad*4+reg (verified m89/m91).
__global__ __launch_bounds__(256) void gemm_k(
    const float* __restrict__ x, const u16* __restrict__ Wt,
    u16* __restrict__ xw) {
    int wave = threadIdx.x >> 6;
    int tile = blockIdx.x * 4 + wave;
    if (tile >= 6250) return;
    int lane = threadIdx.x & 63;
    int m = lane & 15;
    int quad = lane >> 4;
    int row0 = tile * 16;

    f32x4 acc[8];
#pragma unroll
    for (int nt = 0; nt < 8; ++nt) acc[nt] = (f32x4){0.f, 0.f, 0.f, 0.f};

    for (int k0 = 0; k0 < 128; k0 += 32) {
        int kb = k0 + quad * 8;
        const float* p = x + (size_t)(row0 + m) * C + kb;
        float4 v0 = *(const float4*)p;
        float4 v1 = *(const float4*)(p + 4);
        union { uint4 u; s16x8 v; } a;
        a.u.x = (u32)f2bf(v0.x) | ((u32)f2bf(v0.y) << 16);
        a.u.y = (u32)f2bf(v0.z) | ((u32)f2bf(v0.w) << 16);
        a.u.z = (u32)f2bf(v1.x) | ((u32)f2bf(v1.y) << 16);
        a.u.w = (u32)f2bf(v1.z) | ((u32)f2bf(v1.w) << 16);
#pragma unroll
        for (int nt = 0; nt < 8; ++nt) {
            union { uint4 u; s16x8 v; } b;
            b.u = *(const uint4*)(Wt + (size_t)(nt * 16 + m) * C + kb);
            acc[nt] = __builtin_amdgcn_mfma_f32_16x16x32_bf16(a.v, b.v, acc[nt], 0, 0, 0);
        }
    }

#pragma unroll
    for (int nt = 0; nt < 8; ++nt) {
#pragma unroll
        for (int r = 0; r < 4; ++r) {
            int row = row0 + quad * 4 + r;
            xw[(size_t)row * C + nt * 16 + m] = f2bf(acc[nt][r]);
        }
    }
}

// ---------------- hist+rank: the ONLY atomic pass -------------------------
// r = atomicAdd returns within-(bin,key) rank; ranks stored coalesced.
// Counters replicated per bin (bin = blockIdx&7 ~ XCD via round-robin
// dispatch): if atomic cost is cross-XCD line bounce this fixes it; if it's
// raw device-atomic rate this stays ~70us (theory A vs B discriminator).
__global__ __launch_bounds__(256) void hist_rank_k(
    const int* __restrict__ ni, const int* __restrict__ ei,
    u32* __restrict__ cnt, u32* __restrict__ rE, u32* __restrict__ rN,
    int nnz) {
    int i = blockIdx.x * 256 + threadIdx.x;
    if (i >= nnz) return;
    u32* c = cnt + (size_t)(blockIdx.x & 7) * NCNT;
    rE[i] = atomicAdd(&c[ei[i]], 1u);
    rN[i] = atomicAdd(&c[N_EDGES + ni[i]], 1u);
}

// ---------------- scan A: per-key totals + per-bin bases (in-place) -------
// For key k (4 per thread): cntT[k] = sum over bins; cnt[b][k] is overwritten
// with base_local[b][k] = block-local exclusive key prefix + sum_{b'<b}
// cnt[b'][k]. Final global position = cnt[b][k] + bsum[k>>10] + rank.
// Note cnt[0][k] (bin 0) = exclusive key prefix -> gathers use it as start.
__global__ __launch_bounds__(256) void scan_a(u32* __restrict__ cnt,
                                              u32* __restrict__ cntT,
                                              u32* __restrict__ bsum) {
    __shared__ u32 wsum[4];
    int tid = threadIdx.x;
    int base = blockIdx.x * 1024 + tid * 4;
    bool full = (base + 3 < NCNT);
    u32 cb[8][4];
    u32 t0 = 0, t1 = 0, t2 = 0, t3 = 0;
#pragma unroll
    for (int b = 0; b < 8; ++b) {
        uint4 v = make_uint4(0, 0, 0, 0);
        const u32* p = cnt + (size_t)b * NCNT;
        if (full) {
            v = *(const uint4*)(p + base);
        } else {
            if (base + 0 < NCNT) v.x = p[base + 0];
            if (base + 1 < NCNT) v.y = p[base + 1];
            if (base + 2 < NCNT) v.z = p[base + 2];
            if (base + 3 < NCNT) v.w = p[base + 3];
        }
        cb[b][0] = v.x; cb[b][1] = v.y; cb[b][2] = v.z; cb[b][3] = v.w;
        t0 += v.x; t1 += v.y; t2 += v.z; t3 += v.w;
    }
    u32 s = t0 + t1 + t2 + t3;
    int lane = tid & 63, wv = tid >> 6;
    u32 x = s;
    for (int d = 1; d < 64; d <<= 1) {
        u32 y = __shfl_up(x, (unsigned)d);
        if (lane >= d) x += y;
    }
    if (lane == 63) wsum[wv] = x;
    __syncthreads();
    u32 wo = 0;
    for (int w = 0; w < 4; ++w) wo += (w < wv) ? wsum[w] : 0u;
    u32 ex = wo + x - s;

    if (base + 0 < NCNT) cntT[base + 0] = t0;
    if (base + 1 < NCNT) cntT[base + 1] = t1;
    if (base + 2 < NCNT) cntT[base + 2] = t2;
    if (base + 3 < NCNT) cntT[base + 3] = t3;

    u32 run0 = ex, run1 = ex + t0, run2 = ex + t0 + t1, run3 = ex + t0 + t1 + t2;
#pragma unroll
    for (int b = 0; b < 8; ++b) {
        u32* p = cnt + (size_t)b * NCNT;
        if (full) {
            *(uint4*)(p + base) = make_uint4(run0, run1, run2, run3);
        } else {
            if (base + 0 < NCNT) p[base + 0] = run0;
            if (base + 1 < NCNT) p[base + 1] = run1;
            if (base + 2 < NCNT) p[base + 2] = run2;
            if (base + 3 < NCNT) p[base + 3] = run3;
        }
        run0 += cb[b][0]; run1 += cb[b][1]; run2 += cb[b][2]; run3 += cb[b][3];
    }
    if (tid == 255) bsum[blockIdx.x] = wo + x;  // block total
}

// ---------------- scan B: exclusive scan of the 147 block sums ------------
__global__ __launch_bounds__(256) void scan_b(u32* __restrict__ bsum) {
    __shared__ u32 wsum[4];
    int tid = threadIdx.x;
    u32 s = (tid < SCAN_BLOCKS) ? bsum[tid] : 0u;
    int lane = tid & 63, wv = tid >> 6;
    u32 x = s;
    for (int d = 1; d < 64; d <<= 1) {
        u32 y = __shfl_up(x, (unsigned)d);
        if (lane >= d) x += y;
    }
    if (lane == 63) wsum[wv] = x;
    __syncthreads();
    u32 wo = 0;
    for (int w = 0; w < 4; ++w) wo += (w < wv) ? wsum[w] : 0u;
    if (tid < SCAN_BLOCKS) bsum[tid] = wo + x - s;  // exclusive prefix
}

// ---------------- scatter: ATOMIC-FREE (position = base + stored rank) ----
// Same grid/block mapping as hist_rank_k so bin = blockIdx&7 matches.
// Edge entries -> csrE[0..nnz) (value=node); node entries -> csrN (combined
// position minus nnz, value=edge). Pure loads + 2 random 4B stores: isolates
// scattered-write cost from atomic cost.
__global__ __launch_bounds__(256) void scatter_k(
    const int* __restrict__ ni, const int* __restrict__ ei,
    const u32* __restrict__ baseL, const u32* __restrict__ bsum,
    const u32* __restrict__ rE, const u32* __restrict__ rN,
    u32* __restrict__ csrE, u32* __restrict__ csrN, int nnz) {
    int i = blockIdx.x * 256 + threadIdx.x;
    if (i >= nnz) return;
    const u32* b = baseL + (size_t)(blockIdx.x & 7) * NCNT;
    int e = ei[i], n = ni[i];
    u32 posE = b[e] + bsum[e >> 10] + rE[i];
    csrE[posE] = (u32)n;
    int j = N_EDGES + n;
    u32 posN = b[j] + bsum[j >> 10] + rN[i] - (u32)nnz;
    csrN[posN] = (u32)e;
}

// ---------------- edge gather over CSR: 1 edge per wave -------------------
// ef[e] = bf16(B^-1_e * sum xw[nodes of e]); lane owns channels {2l,2l+1}.
// Coalesced 64-wide index load + shfl broadcast; 4-deep unroll for MLP.
__global__ __launch_bounds__(256) void edge_gather_k(const u16* __restrict__ xw,
                                                     const u32* __restrict__ cntT,
                                                     const u32* __restrict__ baseL,
                                                     const u32* __restrict__ bsum,
                                                     const u32* __restrict__ csrE,
                                                     u16* __restrict__ ef) {
    int e = blockIdx.x * 4 + (threadIdx.x >> 6);
    if (e >= N_EDGES) return;
    int lane = threadIdx.x & 63;
    u32 deg = cntT[e];
    u32 start = baseL[e] + bsum[e >> 10];  // baseL = bin-0 table = key prefix
    float ax = 0.f, ay = 0.f;
    for (u32 base = 0; base < deg; base += 64) {
        int m = (int)min(64u, deg - base);
        int myidx = (lane < m) ? (int)csrE[start + base + lane] : 0;
        int t = 0;
        for (; t + 3 < m; t += 4) {
            int r0 = __shfl(myidx, t);
            int r1 = __shfl(myidx, t + 1);
            int r2 = __shfl(myidx, t + 2);
            int r3 = __shfl(myidx, t + 3);
            u32 u0 = ((const u32*)(xw + (size_t)r0 * C))[lane];
            u32 u1 = ((const u32*)(xw + (size_t)r1 * C))[lane];
            u32 u2 = ((const u32*)(xw + (size_t)r2 * C))[lane];
            u32 u3 = ((const u32*)(xw + (size_t)r3 * C))[lane];
            ax += bf2f((u16)(u0 & 0xffffu)) + bf2f((u16)(u1 & 0xffffu)) +
                  bf2f((u16)(u2 & 0xffffu)) + bf2f((u16)(u3 & 0xffffu));
            ay += bf2f((u16)(u0 >> 16)) + bf2f((u16)(u1 >> 16)) +
                  bf2f((u16)(u2 >> 16)) + bf2f((u16)(u3 >> 16));
        }
        for (; t < m; ++t) {
            int r = __shfl(myidx, t);
            u32 u = ((const u32*)(xw + (size_t)r * C))[lane];
            ax += bf2f((u16)(u & 0xffffu));
            ay += bf2f((u16)(u >> 16));
        }
    }
    float sc = deg ? 1.f / (float)deg : 0.f;
    ((u32*)(ef + (size_t)e * C))[lane] =
        (u32)f2bf(ax * sc) | ((u32)f2bf(ay * sc) << 16);
}

// ---------------- node gather over CSR: 1 node per wave -------------------
// out[v] = f32( D^-1_v * sum ef[edges of v] + b ). baseL is the BIN-0 table
// (cnt), indexed at j = N_EDGES + v (round-3 crash: passing cnt+N_EDGES
// double-offset this and read garbage).
__global__ __launch_bounds__(256) void node_gather_k(const u16* __restrict__ ef,
                                                     const u32* __restrict__ cntT,
                                                     const u32* __restrict__ baseL,
                                                     const u32* __restrict__ bsum,
                                                     const u32* __restrict__ csrN,
                                                     const float* __restrict__ bias,
                                                     float* __restrict__ out, int nnz) {
    int v = blockIdx.x * 4 + (threadIdx.x >> 6);
    if (v >= N_NODES) return;
    int lane = threadIdx.x & 63;
    int j = N_EDGES + v;
    u32 deg = cntT[j];
    u32 start = baseL[j] + bsum[j >> 10] - (u32)nnz;  // csrN-local base
    float ax = 0.f, ay = 0.f;
    for (u32 base = 0; base < deg; base += 64) {
        int m = (int)min(64u, deg - base);
        int myidx = (lane < m) ? (int)csrN[start + base + lane] : 0;
        int t = 0;
        for (; t + 3 < m; t += 4) {
            int r0 = __shfl(myidx, t);
            int r1 = __shfl(myidx, t + 1);
            int r2 = __shfl(myidx, t + 2);
            int r3 = __shfl(myidx, t + 3);
            u32 u0 = ((const u32*)(ef + (size_t)r0 * C))[lane];
            u32 u1 = ((const u32*)(ef + (size_t)r1 * C))[lane];
            u32 u2 = ((const u32*)(ef + (size_t)r2 * C))[lane];
            u32 u3 = ((const u32*)(ef + (size_t)r3 * C))[lane];
            ax += bf2f((u16)(u0 & 0xffffu)) + bf2f((u16)(u1 & 0xffffu)) +
                  bf2f((u16)(u2 & 0xffffu)) + bf2f((u16)(u3 & 0xffffu));
            ay += bf2f((u16)(u0 >> 16)) + bf2f((u16)(u1 >> 16)) +
                  bf2f((u16)(u2 >> 16)) + bf2f((u16)(u3 >> 16));
        }
        for (; t < m; ++t) {
            int r = __shfl(myidx, t);
            u32 u = ((const u32*)(ef + (size_t)r * C))[lane];
            ax += bf2f((u16)(u & 0xffffu));
            ay += bf2f((u16)(u >> 16));
        }
    }
    float b0 = bias[2 * lane], b1 = bias[2 * lane + 1];
    float sc = deg ? 1.f / (float)deg : 0.f;
    float2 r;
    r.x = ax * sc + b0;
    r.y = ay * sc + b1;
    ((float2*)(out + (size_t)v * C))[lane] = r;
}

extern "C" void kernel_launch(void* const* d_in, const int* in_sizes, int n_in,
                              void* d_out, int out_size, void* d_ws, size_t ws_size,
                              hipStream_t stream) {
    const float* x = (const float*)d_in[0];     // [N_NODES,128] f32
    const int* node_idx = (const int*)d_in[1];  // [2, NNZ] row-major int32
    const int nnz = in_sizes[1] / 2;
    const int* edge_idx = node_idx + nnz;
    const float* W = (const float*)d_in[2];     // [128,128] f32
    const float* bias = (const float*)d_in[3];  // [128] f32
    float* out = (float*)d_out;                 // [N_NODES,128] f32

    // workspace layout (~20.2 MB)
    u16* Wt = (u16*)d_ws;                           // 16384 u16 (32 KB)
    u16* ef = Wt + 16384;                           // 6.4M u16 (12.8 MB)
    u32* cnt = (u32*)(ef + (size_t)N_EDGES * C);    // 8 x 150000 u32 (4.8 MB)
    u32* cntT = cnt + (size_t)NBIN * NCNT;          // 150000 u32 (600 KB)
    u32* bsum = cntT + NCNT;                        // 147 u32 (pad 256)
    u32* csrN = bsum + 256;                         // nnz u32 (2 MB)

    // d_out (51.2 MB f32) doubles as scratch:
    //   [0, 25.6 MB):      xw bf16 — consumed by edge_gather
    //   [25.6, 27.6 MB):   csrE    — consumed by edge_gather
    //   [27.6, 29.6 MB):   rE      — consumed by scatter
    //   [29.6, 31.6 MB):   rN      — consumed by scatter
    // node_gather then overwrites the whole buffer with the f32 output.
    u16* xw = (u16*)d_out;
    u32* csrE = (u32*)((char*)d_out + (size_t)N_NODES * C * 2);
    u32* rE = csrE + nnz;
    u32* rN = rE + nnz;

    int nBuild = (nnz + 255) / 256;

    hipMemsetAsync(cnt, 0, (size_t)NBIN * NCNT * 4, stream);
    transpose_w<<<64, 256, 0, stream>>>(W, Wt);
    gemm_k<<<G_GEMM, 256, 0, stream>>>(x, Wt, xw);
    hist_rank_k<<<nBuild, 256, 0, stream>>>(node_idx, edge_idx, cnt, rE, rN, nnz);
    scan_a<<<SCAN_BLOCKS, 256, 0, stream>>>(cnt, cntT, bsum);
    scan_b<<<1, 256, 0, stream>>>(bsum);
    scatter_k<<<nBuild, 256, 0, stream>>>(node_idx, edge_idx, cnt, bsum, rE, rN,
                                          csrE, csrN, nnz);
    // 1 edge/node per wave, 4 waves per block
    edge_gather_k<<<(N_EDGES + 3) / 4, 256, 0, stream>>>(xw, cntT, cnt, bsum, csrE, ef);
    node_gather_k<<<(N_NODES + 3) / 4, 256, 0, stream>>>(ef, cntT, cnt, bsum, csrN,
                                                         bias, out, nnz);
}

// Round 5
// 255.211 us; speedup vs baseline: 1.1301x; 1.0024x over previous
//
#include <hip/hip_runtime.h>

typedef unsigned short u16;
typedef unsigned int u32;

#define N_NODES 100000
#define N_EDGES 50000
#define C 128
#define G_GEMM 1563               // 1563 blocks * 4 waves = 6252 tiles >= 6250
#define NCNT (N_EDGES + N_NODES)  // 150000 combined key space (edges then nodes)
#define NBIN 8                    // XCD-replicated counter copies
#define SCAN_BLOCKS ((NCNT + 1023) >> 10)  // 147

static __device__ __forceinline__ float bf2f(u16 h) {
    u32 u = ((u32)h) << 16;
    float f;
    __builtin_memcpy(&f, &u, 4);
    return f;
}

static __device__ __forceinline__ u16 f2bf(float f) {
    u32 u;
    __builtin_memcpy(&u, &f, 4);
    return (u16)((u + 0x7fffu + ((u >> 16) & 1u)) >> 16);  // RNE
}

typedef short s16x8 __attribute__((ext_vector_type(8)));
typedef float f32x4 __attribute__((ext_vector_type(4)));

// ---------------- W transpose -> bf16: Wt[oc][k] = bf16(W[k][oc]) ----------
__global__ void transpose_w(const float* __restrict__ W, u16* __restrict__ Wt) {
    int idx = blockIdx.x * 256 + threadIdx.x;  // 16384 total
    int k = idx >> 7, oc = idx & 127;
    Wt[oc * 128 + k] = f2bf(W[k * 128 + oc]);
}

// ---------------- fused: MFMA GEMM + hist/rank in tail blocks --------------
// Round-4 attribution: gemm standalone = 45us LATENCY-bound (2 outstanding
// loads/wave, 40 VGPR). Fix 1: hoist all 8 x-loads upfront (8 outstanding).
// Fix 2: hist rides in tail blocks - round-2 evidence says the GEMM's idle
// issue slots absorb it (fused 72 < 45+40 split).
// GEMM: xw[n][oc] = x[n][:] . W[:][oc], bf16 out. One wave per 16-row tile;
// A[m=lane&15][k=quad*8+j]; D col=lane&15, row=quad*4+reg (verified m89/m91).
// Hist: bin = (blockIdx-G_GEMM)&7 == scatter's blockIdx&7 for the same i.
__global__ __launch_bounds__(256) void fused_gemm_hist(
    const float* __restrict__ x, const u16* __restrict__ Wt,
    u16* __restrict__ xw,
    const int* __restrict__ ni, const int* __restrict__ ei,
    u32* __restrict__ cnt, u32* __restrict__ rE, u32* __restrict__ rN,
    int nnz) {
    if ((int)blockIdx.x >= G_GEMM) {
        int bb = blockIdx.x - G_GEMM;
        int i = bb * 256 + threadIdx.x;
        if (i < nnz) {
            u32* c = cnt + (size_t)(bb & 7) * NCNT;
            rE[i] = atomicAdd(&c[ei[i]], 1u);
            rN[i] = atomicAdd(&c[N_EDGES + ni[i]], 1u);
        }
        return;
    }
    int wave = threadIdx.x >> 6;
    int tile = blockIdx.x * 4 + wave;
    if (tile >= 6250) return;
    int lane = threadIdx.x & 63;
    int m = lane & 15;
    int quad = lane >> 4;
    int row0 = tile * 16;

    // Hoist ALL x loads for this wave's 16x128 A-tile: 8 dwordx4 in flight.
    const float* xrow = x + (size_t)(row0 + m) * C + quad * 8;
    float4 xv[8];
#pragma unroll
    for (int kk = 0; kk < 4; ++kk) {
        xv[2 * kk]     = *(const float4*)(xrow + kk * 32);
        xv[2 * kk + 1] = *(const float4*)(xrow + kk * 32 + 4);
    }

    f32x4 acc[8];
#pragma unroll
    for (int nt = 0; nt < 8; ++nt) acc[nt] = (f32x4){0.f, 0.f, 0.f, 0.f};

    // Convert to bf16 A-fragments (static indexing only).
    union { uint4 u; s16x8 v; } a[4];
#pragma unroll
    for (int kk = 0; kk < 4; ++kk) {
        float4 v0 = xv[2 * kk], v1 = xv[2 * kk + 1];
        a[kk].u.x = (u32)f2bf(v0.x) | ((u32)f2bf(v0.y) << 16);
        a[kk].u.y = (u32)f2bf(v0.z) | ((u32)f2bf(v0.w) << 16);
        a[kk].u.z = (u32)f2bf(v1.x) | ((u32)f2bf(v1.y) << 16);
        a[kk].u.w = (u32)f2bf(v1.z) | ((u32)f2bf(v1.w) << 16);
    }

#pragma unroll
    for (int kk = 0; kk < 4; ++kk) {
        int kb = kk * 32 + quad * 8;
#pragma unroll
        for (int nt = 0; nt < 8; ++nt) {
            union { uint4 u; s16x8 v; } b;
            b.u = *(const uint4*)(Wt + (size_t)(nt * 16 + m) * C + kb);
            acc[nt] = __builtin_amdgcn_mfma_f32_16x16x32_bf16(a[kk].v, b.v, acc[nt], 0, 0, 0);
        }
    }

#pragma unroll
    for (int nt = 0; nt < 8; ++nt) {
#pragma unroll
        for (int r = 0; r < 4; ++r) {
            int row = row0 + quad * 4 + r;
            xw[(size_t)row * C + nt * 16 + m] = f2bf(acc[nt][r]);
        }
    }
}

// ---------------- scan A: per-key totals + per-bin bases (in-place) -------
// For key k (4 per thread): cntT[k] = sum over bins; cnt[b][k] is overwritten
// with base_local[b][k] = block-local exclusive key prefix + sum_{b'<b}
// cnt[b'][k]. Final global position = cnt[b][k] + bsum[k>>10] + rank.
// Note cnt[0][k] (bin 0) = exclusive key prefix -> gathers use it as start.
__global__ __launch_bounds__(256) void scan_a(u32* __restrict__ cnt,
                                              u32* __restrict__ cntT,
                                              u32* __restrict__ bsum) {
    __shared__ u32 wsum[4];
    int tid = threadIdx.x;
    int base = blockIdx.x * 1024 + tid * 4;
    bool full = (base + 3 < NCNT);
    u32 cb[8][4];
    u32 t0 = 0, t1 = 0, t2 = 0, t3 = 0;
#pragma unroll
    for (int b = 0; b < 8; ++b) {
        uint4 v = make_uint4(0, 0, 0, 0);
        const u32* p = cnt + (size_t)b * NCNT;
        if (full) {
            v = *(const uint4*)(p + base);
        } else {
            if (base + 0 < NCNT) v.x = p[base + 0];
            if (base + 1 < NCNT) v.y = p[base + 1];
            if (base + 2 < NCNT) v.z = p[base + 2];
            if (base + 3 < NCNT) v.w = p[base + 3];
        }
        cb[b][0] = v.x; cb[b][1] = v.y; cb[b][2] = v.z; cb[b][3] = v.w;
        t0 += v.x; t1 += v.y; t2 += v.z; t3 += v.w;
    }
    u32 s = t0 + t1 + t2 + t3;
    int lane = tid & 63, wv = tid >> 6;
    u32 x = s;
    for (int d = 1; d < 64; d <<= 1) {
        u32 y = __shfl_up(x, (unsigned)d);
        if (lane >= d) x += y;
    }
    if (lane == 63) wsum[wv] = x;
    __syncthreads();
    u32 wo = 0;
    for (int w = 0; w < 4; ++w) wo += (w < wv) ? wsum[w] : 0u;
    u32 ex = wo + x - s;

    if (base + 0 < NCNT) cntT[base + 0] = t0;
    if (base + 1 < NCNT) cntT[base + 1] = t1;
    if (base + 2 < NCNT) cntT[base + 2] = t2;
    if (base + 3 < NCNT) cntT[base + 3] = t3;

    u32 run0 = ex, run1 = ex + t0, run2 = ex + t0 + t1, run3 = ex + t0 + t1 + t2;
#pragma unroll
    for (int b = 0; b < 8; ++b) {
        u32* p = cnt + (size_t)b * NCNT;
        if (full) {
            *(uint4*)(p + base) = make_uint4(run0, run1, run2, run3);
        } else {
            if (base + 0 < NCNT) p[base + 0] = run0;
            if (base + 1 < NCNT) p[base + 1] = run1;
            if (base + 2 < NCNT) p[base + 2] = run2;
            if (base + 3 < NCNT) p[base + 3] = run3;
        }
        run0 += cb[b][0]; run1 += cb[b][1]; run2 += cb[b][2]; run3 += cb[b][3];
    }
    if (tid == 255) bsum[blockIdx.x] = wo + x;  // block total
}

// ---------------- scan B: exclusive scan of the 147 block sums ------------
__global__ __launch_bounds__(256) void scan_b(u32* __restrict__ bsum) {
    __shared__ u32 wsum[4];
    int tid = threadIdx.x;
    u32 s = (tid < SCAN_BLOCKS) ? bsum[tid] : 0u;
    int lane = tid & 63, wv = tid >> 6;
    u32 x = s;
    for (int d = 1; d < 64; d <<= 1) {
        u32 y = __shfl_up(x, (unsigned)d);
        if (lane >= d) x += y;
    }
    if (lane == 63) wsum[wv] = x;
    __syncthreads();
    u32 wo = 0;
    for (int w = 0; w < 4; ++w) wo += (w < wv) ? wsum[w] : 0u;
    if (tid < SCAN_BLOCKS) bsum[tid] = wo + x - s;  // exclusive prefix
}

// ---------------- scatter: ATOMIC-FREE (position = base + stored rank) ----
// blockIdx.x here == bb in fused hist, so bin = blockIdx&7 matches.
// Edge entries -> csrE[0..nnz) (value=node); node entries -> csrN (combined
// position minus nnz, value=edge). Pure loads + 2 random 4B stores.
__global__ __launch_bounds__(256) void scatter_k(
    const int* __restrict__ ni, const int* __restrict__ ei,
    const u32* __restrict__ baseL, const u32* __restrict__ bsum,
    const u32* __restrict__ rE, const u32* __restrict__ rN,
    u32* __restrict__ csrE, u32* __restrict__ csrN, int nnz) {
    int i = blockIdx.x * 256 + threadIdx.x;
    if (i >= nnz) return;
    const u32* b = baseL + (size_t)(blockIdx.x & 7) * NCNT;
    int e = ei[i], n = ni[i];
    u32 posE = b[e] + bsum[e >> 10] + rE[i];
    csrE[posE] = (u32)n;
    int j = N_EDGES + n;
    u32 posN = b[j] + bsum[j >> 10] + rN[i] - (u32)nnz;
    csrN[posN] = (u32)e;
}

// ---------------- edge gather over CSR: 1 edge per wave -------------------
// ef[e] = bf16(B^-1_e * sum xw[nodes of e]); lane owns channels {2l,2l+1}.
// Coalesced 64-wide index load + shfl broadcast; 4-deep unroll for MLP.
__global__ __launch_bounds__(256) void edge_gather_k(const u16* __restrict__ xw,
                                                     const u32* __restrict__ cntT,
                                                     const u32* __restrict__ baseL,
                                                     const u32* __restrict__ bsum,
                                                     const u32* __restrict__ csrE,
                                                     u16* __restrict__ ef) {
    int e = blockIdx.x * 4 + (threadIdx.x >> 6);
    if (e >= N_EDGES) return;
    int lane = threadIdx.x & 63;
    u32 deg = cntT[e];
    u32 start = baseL[e] + bsum[e >> 10];  // baseL = bin-0 table = key prefix
    float ax = 0.f, ay = 0.f;
    for (u32 base = 0; base < deg; base += 64) {
        int m = (int)min(64u, deg - base);
        int myidx = (lane < m) ? (int)csrE[start + base + lane] : 0;
        int t = 0;
        for (; t + 3 < m; t += 4) {
            int r0 = __shfl(myidx, t);
            int r1 = __shfl(myidx, t + 1);
            int r2 = __shfl(myidx, t + 2);
            int r3 = __shfl(myidx, t + 3);
            u32 u0 = ((const u32*)(xw + (size_t)r0 * C))[lane];
            u32 u1 = ((const u32*)(xw + (size_t)r1 * C))[lane];
            u32 u2 = ((const u32*)(xw + (size_t)r2 * C))[lane];
            u32 u3 = ((const u32*)(xw + (size_t)r3 * C))[lane];
            ax += bf2f((u16)(u0 & 0xffffu)) + bf2f((u16)(u1 & 0xffffu)) +
                  bf2f((u16)(u2 & 0xffffu)) + bf2f((u16)(u3 & 0xffffu));
            ay += bf2f((u16)(u0 >> 16)) + bf2f((u16)(u1 >> 16)) +
                  bf2f((u16)(u2 >> 16)) + bf2f((u16)(u3 >> 16));
        }
        for (; t < m; ++t) {
            int r = __shfl(myidx, t);
            u32 u = ((const u32*)(xw + (size_t)r * C))[lane];
            ax += bf2f((u16)(u & 0xffffu));
            ay += bf2f((u16)(u >> 16));
        }
    }
    float sc = deg ? 1.f / (float)deg : 0.f;
    ((u32*)(ef + (size_t)e * C))[lane] =
        (u32)f2bf(ax * sc) | ((u32)f2bf(ay * sc) << 16);
}

// ---------------- node gather over CSR: 1 node per wave -------------------
// out[v] = f32( D^-1_v * sum ef[edges of v] + b ). baseL is the BIN-0 table
// (cnt), indexed at j = N_EDGES + v.
__global__ __launch_bounds__(256) void node_gather_k(const u16* __restrict__ ef,
                                                     const u32* __restrict__ cntT,
                                                     const u32* __restrict__ baseL,
                                                     const u32* __restrict__ bsum,
                                                     const u32* __restrict__ csrN,
                                                     const float* __restrict__ bias,
                                                     float* __restrict__ out, int nnz) {
    int v = blockIdx.x * 4 + (threadIdx.x >> 6);
    if (v >= N_NODES) return;
    int lane = threadIdx.x & 63;
    int j = N_EDGES + v;
    u32 deg = cntT[j];
    u32 start = baseL[j] + bsum[j >> 10] - (u32)nnz;  // csrN-local base
    float ax = 0.f, ay = 0.f;
    for (u32 base = 0; base < deg; base += 64) {
        int m = (int)min(64u, deg - base);
        int myidx = (lane < m) ? (int)csrN[start + base + lane] : 0;
        int t = 0;
        for (; t + 3 < m; t += 4) {
            int r0 = __shfl(myidx, t);
            int r1 = __shfl(myidx, t + 1);
            int r2 = __shfl(myidx, t + 2);
            int r3 = __shfl(myidx, t + 3);
            u32 u0 = ((const u32*)(ef + (size_t)r0 * C))[lane];
            u32 u1 = ((const u32*)(ef + (size_t)r1 * C))[lane];
            u32 u2 = ((const u32*)(ef + (size_t)r2 * C))[lane];
            u32 u3 = ((const u32*)(ef + (size_t)r3 * C))[lane];
            ax += bf2f((u16)(u0 & 0xffffu)) + bf2f((u16)(u1 & 0xffffu)) +
                  bf2f((u16)(u2 & 0xffffu)) + bf2f((u16)(u3 & 0xffffu));
            ay += bf2f((u16)(u0 >> 16)) + bf2f((u16)(u1 >> 16)) +
                  bf2f((u16)(u2 >> 16)) + bf2f((u16)(u3 >> 16));
        }
        for (; t < m; ++t) {
            int r = __shfl(myidx, t);
            u32 u = ((const u32*)(ef + (size_t)r * C))[lane];
            ax += bf2f((u16)(u & 0xffffu));
            ay += bf2f((u16)(u >> 16));
        }
    }
    float b0 = bias[2 * lane], b1 = bias[2 * lane + 1];
    float sc = deg ? 1.f / (float)deg : 0.f;
    float2 r;
    r.x = ax * sc + b0;
    r.y = ay * sc + b1;
    ((float2*)(out + (size_t)v * C))[lane] = r;
}

extern "C" void kernel_launch(void* const* d_in, const int* in_sizes, int n_in,
                              void* d_out, int out_size, void* d_ws, size_t ws_size,
                              hipStream_t stream) {
    const float* x = (const float*)d_in[0];     // [N_NODES,128] f32
    const int* node_idx = (const int*)d_in[1];  // [2, NNZ] row-major int32
    const int nnz = in_sizes[1] / 2;
    const int* edge_idx = node_idx + nnz;
    const float* W = (const float*)d_in[2];     // [128,128] f32
    const float* bias = (const float*)d_in[3];  // [128] f32
    float* out = (float*)d_out;                 // [N_NODES,128] f32

    // workspace layout (~20.2 MB)
    u16* Wt = (u16*)d_ws;                           // 16384 u16 (32 KB)
    u16* ef = Wt + 16384;                           // 6.4M u16 (12.8 MB)
    u32* cnt = (u32*)(ef + (size_t)N_EDGES * C);    // 8 x 150000 u32 (4.8 MB)
    u32* cntT = cnt + (size_t)NBIN * NCNT;          // 150000 u32 (600 KB)
    u32* bsum = cntT + NCNT;                        // 147 u32 (pad 256)
    u32* csrN = bsum + 256;                         // nnz u32 (2 MB)

    // d_out (51.2 MB f32) doubles as scratch:
    //   [0, 25.6 MB):      xw bf16 — consumed by edge_gather
    //   [25.6, 27.6 MB):   csrE    — consumed by edge_gather
    //   [27.6, 29.6 MB):   rE      — consumed by scatter
    //   [29.6, 31.6 MB):   rN      — consumed by scatter
    // node_gather then overwrites the whole buffer with the f32 output.
    u16* xw = (u16*)d_out;
    u32* csrE = (u32*)((char*)d_out + (size_t)N_NODES * C * 2);
    u32* rE = csrE + nnz;
    u32* rN = rE + nnz;

    int nBuild = (nnz + 255) / 256;

    hipMemsetAsync(cnt, 0, (size_t)NBIN * NCNT * 4, stream);
    transpose_w<<<64, 256, 0, stream>>>(W, Wt);
    fused_gemm_hist<<<G_GEMM + nBuild, 256, 0, stream>>>(
        x, Wt, xw, node_idx, edge_idx, cnt, rE, rN, nnz);
    scan_a<<<SCAN_BLOCKS, 256, 0, stream>>>(cnt, cntT, bsum);
    scan_b<<<1, 256, 0, stream>>>(bsum);
    scatter_k<<<nBuild, 256, 0, stream>>>(node_idx, edge_idx, cnt, bsum, rE, rN,
                                          csrE, csrN, nnz);
    // 1 edge/node per wave, 4 waves per block
    edge_gather_k<<<(N_EDGES + 3) / 4, 256, 0, stream>>>(xw, cntT, cnt, bsum, csrE, ef);
    node_gather_k<<<(N_NODES + 3) / 4, 256, 0, stream>>>(ef, cntT, cnt, bsum, csrN,
                                                         bias, out, nnz);
}

// Round 6
// 247.869 us; speedup vs baseline: 1.1636x; 1.0296x over previous
//
#include <hip/hip_runtime.h>

typedef unsigned short u16;
typedef unsigned int u32;

#define N_NODES 100000
#define N_EDGES 50000
#define C 128
#define G_GEMM 1563               // 1563 blocks * 4 waves = 6252 tiles >= 6250
#define NCNT (N_EDGES + N_NODES)  // 150000 combined key space (edges then nodes)
#define NBIN 8                    // XCD-replicated counter copies
#define SCAN_BLOCKS ((NCNT + 1023) >> 10)  // 147

static __device__ __forceinline__ float bf2f(u16 h) {
    u32 u = ((u32)h) << 16;
    float f;
    __builtin_memcpy(&f, &u, 4);
    return f;
}

static __device__ __forceinline__ u16 f2bf(float f) {
    u32 u;
    __builtin_memcpy(&u, &f, 4);
    return (u16)((u + 0x7fffu + ((u >> 16) & 1u)) >> 16);  // RNE
}

typedef short s16x8 __attribute__((ext_vector_type(8)));
typedef float f32x4 __attribute__((ext_vector_type(4)));

// ---------------- W transpose -> bf16: Wt[oc][k] = bf16(W[k][oc]) ----------
__global__ void transpose_w(const float* __restrict__ W, u16* __restrict__ Wt) {
    int idx = blockIdx.x * 256 + threadIdx.x;  // 16384 total
    int k = idx >> 7, oc = idx & 127;
    Wt[oc * 128 + k] = f2bf(W[k * 128 + oc]);
}

// ---------------- GEMM standalone (unfused: r5 fusion gave 0 overlap) ------
// Hoisted x-loads (8 dwordx4 in flight) -- isolated A/B vs round-4's 45us
// non-hoisted 40-VGPR version.
// xw[n][oc] = x[n][:] . W[:][oc], bf16 out. One wave per 16-row tile;
// A[m=lane&15][k=quad*8+j]; D col=lane&15, row=quad*4+reg (verified m89/m91).
__global__ __launch_bounds__(256) void gemm_k(
    const float* __restrict__ x, const u16* __restrict__ Wt,
    u16* __restrict__ xw) {
    int wave = threadIdx.x >> 6;
    int tile = blockIdx.x * 4 + wave;
    if (tile >= 6250) return;
    int lane = threadIdx.x & 63;
    int m = lane & 15;
    int quad = lane >> 4;
    int row0 = tile * 16;

    const float* xrow = x + (size_t)(row0 + m) * C + quad * 8;
    float4 xv[8];
#pragma unroll
    for (int kk = 0; kk < 4; ++kk) {
        xv[2 * kk]     = *(const float4*)(xrow + kk * 32);
        xv[2 * kk + 1] = *(const float4*)(xrow + kk * 32 + 4);
    }

    f32x4 acc[8];
#pragma unroll
    for (int nt = 0; nt < 8; ++nt) acc[nt] = (f32x4){0.f, 0.f, 0.f, 0.f};

    union { uint4 u; s16x8 v; } a[4];
#pragma unroll
    for (int kk = 0; kk < 4; ++kk) {
        float4 v0 = xv[2 * kk], v1 = xv[2 * kk + 1];
        a[kk].u.x = (u32)f2bf(v0.x) | ((u32)f2bf(v0.y) << 16);
        a[kk].u.y = (u32)f2bf(v0.z) | ((u32)f2bf(v0.w) << 16);
        a[kk].u.z = (u32)f2bf(v1.x) | ((u32)f2bf(v1.y) << 16);
        a[kk].u.w = (u32)f2bf(v1.z) | ((u32)f2bf(v1.w) << 16);
    }

#pragma unroll
    for (int kk = 0; kk < 4; ++kk) {
        int kb = kk * 32 + quad * 8;
#pragma unroll
        for (int nt = 0; nt < 8; ++nt) {
            union { uint4 u; s16x8 v; } b;
            b.u = *(const uint4*)(Wt + (size_t)(nt * 16 + m) * C + kb);
            acc[nt] = __builtin_amdgcn_mfma_f32_16x16x32_bf16(a[kk].v, b.v, acc[nt], 0, 0, 0);
        }
    }

#pragma unroll
    for (int nt = 0; nt < 8; ++nt) {
#pragma unroll
        for (int r = 0; r < 4; ++r) {
            int row = row0 + quad * 4 + r;
            xw[(size_t)row * C + nt * 16 + m] = f2bf(acc[nt][r]);
        }
    }
}

// ---------------- hist+rank: the ONLY atomic pass (XCD-binned) -------------
// bin = blockIdx&7 must match scatter_k's mapping (identical grids).
__global__ __launch_bounds__(256) void hist_rank_k(
    const int* __restrict__ ni, const int* __restrict__ ei,
    u32* __restrict__ cnt, u32* __restrict__ rE, u32* __restrict__ rN,
    int nnz) {
    int i = blockIdx.x * 256 + threadIdx.x;
    if (i >= nnz) return;
    u32* c = cnt + (size_t)(blockIdx.x & 7) * NCNT;
    rE[i] = atomicAdd(&c[ei[i]], 1u);
    rN[i] = atomicAdd(&c[N_EDGES + ni[i]], 1u);
}

// ---------------- scan A: per-bin bases (in-place) + rowinfo ---------------
// cnt[b][k] <- base_local[b][k] = block-local exclusive key prefix +
// sum_{b'<b} cnt[b'][k]; scatter position = cnt[b][k] + bsum[k>>10] + rank.
// NEW: rowinfo[k] = {ex_k (== cnt[0][k]), deg_k} so gathers do ONE dependent
// 8B load instead of three 4B loads (cntT/baseL/bsum-chain).
__global__ __launch_bounds__(256) void scan_a(u32* __restrict__ cnt,
                                              uint2* __restrict__ rowinfo,
                                              u32* __restrict__ bsum) {
    __shared__ u32 wsum[4];
    int tid = threadIdx.x;
    int base = blockIdx.x * 1024 + tid * 4;
    bool full = (base + 3 < NCNT);
    u32 cb[8][4];
    u32 t0 = 0, t1 = 0, t2 = 0, t3 = 0;
#pragma unroll
    for (int b = 0; b < 8; ++b) {
        uint4 v = make_uint4(0, 0, 0, 0);
        const u32* p = cnt + (size_t)b * NCNT;
        if (full) {
            v = *(const uint4*)(p + base);
        } else {
            if (base + 0 < NCNT) v.x = p[base + 0];
            if (base + 1 < NCNT) v.y = p[base + 1];
            if (base + 2 < NCNT) v.z = p[base + 2];
            if (base + 3 < NCNT) v.w = p[base + 3];
        }
        cb[b][0] = v.x; cb[b][1] = v.y; cb[b][2] = v.z; cb[b][3] = v.w;
        t0 += v.x; t1 += v.y; t2 += v.z; t3 += v.w;
    }
    u32 s = t0 + t1 + t2 + t3;
    int lane = tid & 63, wv = tid >> 6;
    u32 x = s;
    for (int d = 1; d < 64; d <<= 1) {
        u32 y = __shfl_up(x, (unsigned)d);
        if (lane >= d) x += y;
    }
    if (lane == 63) wsum[wv] = x;
    __syncthreads();
    u32 wo = 0;
    for (int w = 0; w < 4; ++w) wo += (w < wv) ? wsum[w] : 0u;
    u32 ex = wo + x - s;

    // rowinfo: {local exclusive start, total deg} per key (16B-aligned stores)
    if (full) {
        *(uint4*)(rowinfo + base)     = make_uint4(ex, t0, ex + t0, t1);
        *(uint4*)(rowinfo + base + 2) = make_uint4(ex + t0 + t1, t2, ex + t0 + t1 + t2, t3);
    } else {
        if (base + 0 < NCNT) rowinfo[base + 0] = make_uint2(ex, t0);
        if (base + 1 < NCNT) rowinfo[base + 1] = make_uint2(ex + t0, t1);
        if (base + 2 < NCNT) rowinfo[base + 2] = make_uint2(ex + t0 + t1, t2);
        if (base + 3 < NCNT) rowinfo[base + 3] = make_uint2(ex + t0 + t1 + t2, t3);
    }

    u32 run0 = ex, run1 = ex + t0, run2 = ex + t0 + t1, run3 = ex + t0 + t1 + t2;
#pragma unroll
    for (int b = 0; b < 8; ++b) {
        u32* p = cnt + (size_t)b * NCNT;
        if (full) {
            *(uint4*)(p + base) = make_uint4(run0, run1, run2, run3);
        } else {
            if (base + 0 < NCNT) p[base + 0] = run0;
            if (base + 1 < NCNT) p[base + 1] = run1;
            if (base + 2 < NCNT) p[base + 2] = run2;
            if (base + 3 < NCNT) p[base + 3] = run3;
        }
        run0 += cb[b][0]; run1 += cb[b][1]; run2 += cb[b][2]; run3 += cb[b][3];
    }
    if (tid == 255) bsum[blockIdx.x] = wo + x;  // block total
}

// ---------------- scan B: exclusive scan of the 147 block sums ------------
__global__ __launch_bounds__(256) void scan_b(u32* __restrict__ bsum) {
    __shared__ u32 wsum[4];
    int tid = threadIdx.x;
    u32 s = (tid < SCAN_BLOCKS) ? bsum[tid] : 0u;
    int lane = tid & 63, wv = tid >> 6;
    u32 x = s;
    for (int d = 1; d < 64; d <<= 1) {
        u32 y = __shfl_up(x, (unsigned)d);
        if (lane >= d) x += y;
    }
    if (lane == 63) wsum[wv] = x;
    __syncthreads();
    u32 wo = 0;
    for (int w = 0; w < 4; ++w) wo += (w < wv) ? wsum[w] : 0u;
    if (tid < SCAN_BLOCKS) bsum[tid] = wo + x - s;  // exclusive prefix
}

// ---------------- scatter: ATOMIC-FREE (position = base + stored rank) ----
// blockIdx&7 matches hist_rank_k's bin for the same i (identical grids).
__global__ __launch_bounds__(256) void scatter_k(
    const int* __restrict__ ni, const int* __restrict__ ei,
    const u32* __restrict__ baseL, const u32* __restrict__ bsum,
    const u32* __restrict__ rE, const u32* __restrict__ rN,
    u32* __restrict__ csrE, u32* __restrict__ csrN, int nnz) {
    int i = blockIdx.x * 256 + threadIdx.x;
    if (i >= nnz) return;
    const u32* b = baseL + (size_t)(blockIdx.x & 7) * NCNT;
    int e = ei[i], n = ni[i];
    u32 posE = b[e] + bsum[e >> 10] + rE[i];
    csrE[posE] = (u32)n;
    int j = N_EDGES + n;
    u32 posN = b[j] + bsum[j >> 10] + rN[i] - (u32)nnz;
    csrN[posN] = (u32)e;
}

// ---------------- 8-wide branchless gather body ----------------------------
// Theory r6: the serial per-entry remainder loop (~550cy dependent load each)
// dominated gather time. Every iteration now issues exactly 8 independent
// row loads (indices clamped to m-1, contributions masked 0/1; masks are
// wave-uniform so no divergence). deg=10 -> 2 iterations instead of
// 2 fast + 2 serial.
#define GATHER8(SRC)                                                          \
    for (u32 base = 0; base < deg; base += 64) {                              \
        int m = (int)min(64u, deg - base);                                    \
        int myidx = (lane < m) ? (int)csr[start + base + lane] : 0;           \
        for (int t = 0; t < m; t += 8) {                                      \
            int i1 = min(t + 1, m - 1), i2 = min(t + 2, m - 1);               \
            int i3 = min(t + 3, m - 1), i4 = min(t + 4, m - 1);               \
            int i5 = min(t + 5, m - 1), i6 = min(t + 6, m - 1);               \
            int i7 = min(t + 7, m - 1);                                       \
            int r0 = __shfl(myidx, t),  r1 = __shfl(myidx, i1);               \
            int r2 = __shfl(myidx, i2), r3 = __shfl(myidx, i3);               \
            int r4 = __shfl(myidx, i4), r5 = __shfl(myidx, i5);               \
            int r6 = __shfl(myidx, i6), r7 = __shfl(myidx, i7);               \
            u32 u0 = ((const u32*)(SRC + (size_t)r0 * C))[lane];              \
            u32 u1 = ((const u32*)(SRC + (size_t)r1 * C))[lane];              \
            u32 u2 = ((const u32*)(SRC + (size_t)r2 * C))[lane];              \
            u32 u3 = ((const u32*)(SRC + (size_t)r3 * C))[lane];              \
            u32 u4 = ((const u32*)(SRC + (size_t)r4 * C))[lane];              \
            u32 u5 = ((const u32*)(SRC + (size_t)r5 * C))[lane];              \
            u32 u6 = ((const u32*)(SRC + (size_t)r6 * C))[lane];              \
            u32 u7 = ((const u32*)(SRC + (size_t)r7 * C))[lane];              \
            float k1 = (t + 1 < m) ? 1.f : 0.f, k2 = (t + 2 < m) ? 1.f : 0.f; \
            float k3 = (t + 3 < m) ? 1.f : 0.f, k4 = (t + 4 < m) ? 1.f : 0.f; \
            float k5 = (t + 5 < m) ? 1.f : 0.f, k6 = (t + 6 < m) ? 1.f : 0.f; \
            float k7 = (t + 7 < m) ? 1.f : 0.f;                               \
            ax += bf2f((u16)(u0 & 0xffffu)) + k1 * bf2f((u16)(u1 & 0xffffu))  \
                + k2 * bf2f((u16)(u2 & 0xffffu)) + k3 * bf2f((u16)(u3 & 0xffffu)) \
                + k4 * bf2f((u16)(u4 & 0xffffu)) + k5 * bf2f((u16)(u5 & 0xffffu)) \
                + k6 * bf2f((u16)(u6 & 0xffffu)) + k7 * bf2f((u16)(u7 & 0xffffu)); \
            ay += bf2f((u16)(u0 >> 16)) + k1 * bf2f((u16)(u1 >> 16))          \
                + k2 * bf2f((u16)(u2 >> 16)) + k3 * bf2f((u16)(u3 >> 16))     \
                + k4 * bf2f((u16)(u4 >> 16)) + k5 * bf2f((u16)(u5 >> 16))     \
                + k6 * bf2f((u16)(u6 >> 16)) + k7 * bf2f((u16)(u7 >> 16));    \
        }                                                                     \
    }

// ---------------- edge gather over CSR: 1 edge per wave -------------------
// ef[e] = bf16(B^-1_e * sum xw[nodes of e]); lane owns channels {2l,2l+1}.
__global__ __launch_bounds__(256) void edge_gather_k(const u16* __restrict__ xw,
                                                     const uint2* __restrict__ rowinfo,
                                                     const u32* __restrict__ bsum,
                                                     const u32* __restrict__ csrE,
                                                     u16* __restrict__ ef) {
    int e = blockIdx.x * 4 + (threadIdx.x >> 6);
    if (e >= N_EDGES) return;
    int lane = threadIdx.x & 63;
    uint2 ri = rowinfo[e];
    u32 deg = ri.y;
    u32 start = ri.x + bsum[e >> 10];
    const u32* csr = csrE;
    float ax = 0.f, ay = 0.f;
    GATHER8(xw)
    float sc = deg ? 1.f / (float)deg : 0.f;
    ((u32*)(ef + (size_t)e * C))[lane] =
        (u32)f2bf(ax * sc) | ((u32)f2bf(ay * sc) << 16);
}

// ---------------- node gather over CSR: 1 node per wave -------------------
// out[v] = f32( D^-1_v * sum ef[edges of v] + b )
__global__ __launch_bounds__(256) void node_gather_k(const u16* __restrict__ ef,
                                                     const uint2* __restrict__ rowinfo,
                                                     const u32* __restrict__ bsum,
                                                     const u32* __restrict__ csrN,
                                                     const float* __restrict__ bias,
                                                     float* __restrict__ out, int nnz) {
    int v = blockIdx.x * 4 + (threadIdx.x >> 6);
    if (v >= N_NODES) return;
    int lane = threadIdx.x & 63;
    int j = N_EDGES + v;
    uint2 ri = rowinfo[j];
    u32 deg = ri.y;
    u32 start = ri.x + bsum[j >> 10] - (u32)nnz;  // csrN-local base
    const u32* csr = csrN;
    float ax = 0.f, ay = 0.f;
    GATHER8(ef)
    float b0 = bias[2 * lane], b1 = bias[2 * lane + 1];
    float sc = deg ? 1.f / (float)deg : 0.f;
    float2 r;
    r.x = ax * sc + b0;
    r.y = ay * sc + b1;
    ((float2*)(out + (size_t)v * C))[lane] = r;
}

extern "C" void kernel_launch(void* const* d_in, const int* in_sizes, int n_in,
                              void* d_out, int out_size, void* d_ws, size_t ws_size,
                              hipStream_t stream) {
    const float* x = (const float*)d_in[0];     // [N_NODES,128] f32
    const int* node_idx = (const int*)d_in[1];  // [2, NNZ] row-major int32
    const int nnz = in_sizes[1] / 2;
    const int* edge_idx = node_idx + nnz;
    const float* W = (const float*)d_in[2];     // [128,128] f32
    const float* bias = (const float*)d_in[3];  // [128] f32
    float* out = (float*)d_out;                 // [N_NODES,128] f32

    // workspace layout (~20.9 MB)
    u16* Wt = (u16*)d_ws;                           // 16384 u16 (32 KB)
    u16* ef = Wt + 16384;                           // 6.4M u16 (12.8 MB)
    u32* cnt = (u32*)(ef + (size_t)N_EDGES * C);    // 8 x 150000 u32 (4.8 MB)
    u32* bsum = cnt + (size_t)NBIN * NCNT;          // 147 u32 (pad 256)
    uint2* rowinfo = (uint2*)(bsum + 256);          // 150000 uint2 (1.2 MB)
    u32* csrN = (u32*)(rowinfo + NCNT);             // nnz u32 (2 MB)

    // d_out (51.2 MB f32) doubles as scratch:
    //   [0, 25.6 MB):      xw bf16 — consumed by edge_gather
    //   [25.6, 27.6 MB):   csrE    — consumed by edge_gather
    //   [27.6, 29.6 MB):   rE      — consumed by scatter
    //   [29.6, 31.6 MB):   rN      — consumed by scatter
    // node_gather then overwrites the whole buffer with the f32 output.
    u16* xw = (u16*)d_out;
    u32* csrE = (u32*)((char*)d_out + (size_t)N_NODES * C * 2);
    u32* rE = csrE + nnz;
    u32* rN = rE + nnz;

    int nBuild = (nnz + 255) / 256;

    hipMemsetAsync(cnt, 0, (size_t)NBIN * NCNT * 4, stream);
    transpose_w<<<64, 256, 0, stream>>>(W, Wt);
    gemm_k<<<G_GEMM, 256, 0, stream>>>(x, Wt, xw);
    hist_rank_k<<<nBuild, 256, 0, stream>>>(node_idx, edge_idx, cnt, rE, rN, nnz);
    scan_a<<<SCAN_BLOCKS, 256, 0, stream>>>(cnt, rowinfo, bsum);
    scan_b<<<1, 256, 0, stream>>>(bsum);
    scatter_k<<<nBuild, 256, 0, stream>>>(node_idx, edge_idx, cnt, bsum, rE, rN,
                                          csrE, csrN, nnz);
    // 1 edge/node per wave, 4 waves per block
    edge_gather_k<<<(N_EDGES + 3) / 4, 256, 0, stream>>>(xw, rowinfo, bsum, csrE, ef);
    node_gather_k<<<(N_NODES + 3) / 4, 256, 0, stream>>>(ef, rowinfo, bsum, csrN,
                                                         bias, out, nnz);
}

// Round 7
// 214.086 us; speedup vs baseline: 1.3472x; 1.1578x over previous
//
#include <hip/hip_runtime.h>

typedef unsigned short u16;
typedef unsigned int u32;

#define N_NODES 100000
#define N_EDGES 50000
#define C 128
#define G_GEMM 1563               // 1563 blocks * 4 waves = 6252 tiles >= 6250
#define NCNT (N_EDGES + N_NODES)  // 150000 combined key space (edges then nodes)
#define NBUCKC 1172               // ceil(150000 / 128) coarse buckets (key>>7)
#define BCHUNK 2048               // incidences per bucketize block

static __device__ __forceinline__ float bf2f(u16 h) {
    u32 u = ((u32)h) << 16;
    float f;
    __builtin_memcpy(&f, &u, 4);
    return f;
}

static __device__ __forceinline__ u16 f2bf(float f) {
    u32 u;
    __builtin_memcpy(&u, &f, 4);
    return (u16)((u + 0x7fffu + ((u >> 16) & 1u)) >> 16);  // RNE
}

typedef short s16x8 __attribute__((ext_vector_type(8)));
typedef float f32x4 __attribute__((ext_vector_type(4)));

// ---------------- W transpose -> bf16: Wt[oc][k] = bf16(W[k][oc]) ----------
__global__ void transpose_w(const float* __restrict__ W, u16* __restrict__ Wt) {
    int idx = blockIdx.x * 256 + threadIdx.x;  // 16384 total
    int k = idx >> 7, oc = idx & 127;
    Wt[oc * 128 + k] = f2bf(W[k * 128 + oc]);
}

// ---------------- GEMM (r6 hoisted version, unchanged) --------------------
// xw[n][oc] = x[n][:] . W[:][oc], bf16 out. One wave per 16-row tile;
// A[m=lane&15][k=quad*8+j]; D col=lane&15, row=quad*4+reg (verified m89/m91).
__global__ __launch_bounds__(256) void gemm_k(
    const float* __restrict__ x, const u16* __restrict__ Wt,
    u16* __restrict__ xw) {
    int wave = threadIdx.x >> 6;
    int tile = blockIdx.x * 4 + wave;
    if (tile >= 6250) return;
    int lane = threadIdx.x & 63;
    int m = lane & 15;
    int quad = lane >> 4;
    int row0 = tile * 16;

    const float* xrow = x + (size_t)(row0 + m) * C + quad * 8;
    float4 xv[8];
#pragma unroll
    for (int kk = 0; kk < 4; ++kk) {
        xv[2 * kk]     = *(const float4*)(xrow + kk * 32);
        xv[2 * kk + 1] = *(const float4*)(xrow + kk * 32 + 4);
    }

    f32x4 acc[8];
#pragma unroll
    for (int nt = 0; nt < 8; ++nt) acc[nt] = (f32x4){0.f, 0.f, 0.f, 0.f};

    union { uint4 u; s16x8 v; } a[4];
#pragma unroll
    for (int kk = 0; kk < 4; ++kk) {
        float4 v0 = xv[2 * kk], v1 = xv[2 * kk + 1];
        a[kk].u.x = (u32)f2bf(v0.x) | ((u32)f2bf(v0.y) << 16);
        a[kk].u.y = (u32)f2bf(v0.z) | ((u32)f2bf(v0.w) << 16);
        a[kk].u.z = (u32)f2bf(v1.x) | ((u32)f2bf(v1.y) << 16);
        a[kk].u.w = (u32)f2bf(v1.z) | ((u32)f2bf(v1.w) << 16);
    }

#pragma unroll
    for (int kk = 0; kk < 4; ++kk) {
        int kb = kk * 32 + quad * 8;
#pragma unroll
        for (int nt = 0; nt < 8; ++nt) {
            union { uint4 u; s16x8 v; } b;
            b.u = *(const uint4*)(Wt + (size_t)(nt * 16 + m) * C + kb);
            acc[nt] = __builtin_amdgcn_mfma_f32_16x16x32_bf16(a[kk].v, b.v, acc[nt], 0, 0, 0);
        }
    }

#pragma unroll
    for (int nt = 0; nt < 8; ++nt) {
#pragma unroll
        for (int r = 0; r < 4; ++r) {
            int row = row0 + quad * 4 + r;
            xw[(size_t)row * C + nt * 16 + m] = f2bf(acc[nt][r]);
        }
    }
}

// ---------------- P1a: per-(block,bucket) counts — ZERO global atomics -----
// Theory r7: device-scope atomics run memory-side (~2.4e10/s chip-wide;
// r6 hist WRITE_SIZE 35MB == 1M atomics' fabric traffic). Build CSR with a
// deterministic count-matrix sort instead. LDS histogram only.
__global__ __launch_bounds__(256) void bucket_hist_k(
    const int* __restrict__ ni, const int* __restrict__ ei,
    u32* __restrict__ cntM, int nnz, int nb1) {
    __shared__ u32 h[NBUCKC];
    for (int b = threadIdx.x; b < NBUCKC; b += 256) h[b] = 0;
    __syncthreads();
    int i0 = blockIdx.x * BCHUNK;
    int iend = min(i0 + BCHUNK, nnz);
    for (int i = i0 + threadIdx.x; i < iend; i += 256) {
        int e = ei[i], n = ni[i];
        atomicAdd(&h[e >> 7], 1u);                 // LDS atomic (fast)
        atomicAdd(&h[(N_EDGES + n) >> 7], 1u);
    }
    __syncthreads();
    for (int b = threadIdx.x; b < NBUCKC; b += 256)
        cntM[(size_t)b * nb1 + blockIdx.x] = h[b];  // plain stores
}

// ---------------- scan A: generic exclusive scan (r2-proven structure) -----
__global__ __launch_bounds__(256) void scan_a2(const u32* __restrict__ cnt,
                                               u32* __restrict__ off,
                                               u32* __restrict__ bsum, int N) {
    __shared__ u32 wsum[4];
    int tid = threadIdx.x;
    int base = blockIdx.x * 1024 + tid * 4;
    u32 v0 = 0, v1 = 0, v2 = 0, v3 = 0;
    if (base + 3 < N) {
        uint4 v = *(const uint4*)(cnt + base);
        v0 = v.x; v1 = v.y; v2 = v.z; v3 = v.w;
    } else {
        if (base + 0 < N) v0 = cnt[base + 0];
        if (base + 1 < N) v1 = cnt[base + 1];
        if (base + 2 < N) v2 = cnt[base + 2];
        if (base + 3 < N) v3 = cnt[base + 3];
    }
    u32 s = v0 + v1 + v2 + v3;
    int lane = tid & 63, wv = tid >> 6;
    u32 x = s;
    for (int d = 1; d < 64; d <<= 1) {
        u32 y = __shfl_up(x, (unsigned)d);
        if (lane >= d) x += y;
    }
    if (lane == 63) wsum[wv] = x;
    __syncthreads();
    u32 wo = 0;
    for (int w = 0; w < 4; ++w) wo += (w < wv) ? wsum[w] : 0u;
    u32 ex = wo + x - s;
    if (base + 0 < N) off[base + 0] = ex;
    if (base + 1 < N) off[base + 1] = ex + v0;
    if (base + 2 < N) off[base + 2] = ex + v0 + v1;
    if (base + 3 < N) off[base + 3] = ex + v0 + v1 + v2;
    if (tid == 255) bsum[blockIdx.x] = wo + x;  // block total
}

// ---------------- scan B: exclusive scan of up to 512 block sums ----------
__global__ __launch_bounds__(256) void scan_b2(u32* __restrict__ bsum, int nb) {
    __shared__ u32 wsum[4];
    int t = threadIdx.x;
    u32 v0 = (2 * t < nb) ? bsum[2 * t] : 0u;
    u32 v1 = (2 * t + 1 < nb) ? bsum[2 * t + 1] : 0u;
    u32 s = v0 + v1;
    int lane = t & 63, wv = t >> 6;
    u32 x = s;
    for (int d = 1; d < 64; d <<= 1) {
        u32 y = __shfl_up(x, (unsigned)d);
        if (lane >= d) x += y;
    }
    if (lane == 63) wsum[wv] = x;
    __syncthreads();
    u32 wo = 0;
    for (int w = 0; w < 4; ++w) wo += (w < wv) ? wsum[w] : 0u;
    u32 ex = wo + x - s;
    if (2 * t < nb) bsum[2 * t] = ex;
    if (2 * t + 1 < nb) bsum[2 * t + 1] = ex + v0;
}

// ---------------- P1b: place entries bucket-grouped (LDS cursors only) -----
// pos = offM[bucket][blk] (+bsum) + LDS cursor. Entries packed 4B:
// (key&127)<<17 | val  (val <= 99999 < 2^17).
__global__ __launch_bounds__(256) void bucket_place_k(
    const int* __restrict__ ni, const int* __restrict__ ei,
    const u32* __restrict__ offM, const u32* __restrict__ bsum,
    u32* __restrict__ stage, int nnz, int nb1) {
    __shared__ u32 cur[NBUCKC];
    for (int b = threadIdx.x; b < NBUCKC; b += 256) {
        size_t idx = (size_t)b * nb1 + blockIdx.x;
        cur[b] = offM[idx] + bsum[idx >> 10];
    }
    __syncthreads();
    int i0 = blockIdx.x * BCHUNK;
    int iend = min(i0 + BCHUNK, nnz);
    for (int i = i0 + threadIdx.x; i < iend; i += 256) {
        int e = ei[i], n = ni[i];
        u32 p1 = atomicAdd(&cur[e >> 7], 1u);
        stage[p1] = ((u32)(e & 127) << 17) | (u32)n;
        int k2 = N_EDGES + n;
        u32 p2 = atomicAdd(&cur[k2 >> 7], 1u);
        stage[p2] = ((u32)(k2 & 127) << 17) | (u32)e;
    }
}

// ---------------- P2: per-bucket fine counting-sort -> dense CSR + rowinfo --
// One block per bucket (~853 entries, 128 keys). No capacity assumptions.
// rowinfo[key] = {GLOBAL start in combined csr, deg}. Edge keys sort before
// node keys, so csr[0..nnz) = edge lists, csr[nnz..2nnz) = node lists.
__global__ __launch_bounds__(256) void bucket_csr_k(
    const u32* __restrict__ offM, const u32* __restrict__ bsum,
    const u32* __restrict__ stage, u32* __restrict__ csr,
    uint2* __restrict__ rowinfo, int nnz, int nb1) {
    __shared__ u32 h[128];
    __shared__ u32 ks[128];
    int b = blockIdx.x;
    size_t i0 = (size_t)b * nb1;
    u32 gstart = offM[i0] + bsum[i0 >> 10];
    u32 gend;
    if (b + 1 < NBUCKC) {
        size_t i1 = (size_t)(b + 1) * nb1;
        gend = offM[i1] + bsum[i1 >> 10];
    } else {
        gend = (u32)(2 * nnz);
    }
    int size = (int)(gend - gstart);
    if (threadIdx.x < 128) h[threadIdx.x] = 0;
    __syncthreads();
    for (int i = threadIdx.x; i < size; i += 256)
        atomicAdd(&h[stage[gstart + i] >> 17], 1u);
    __syncthreads();
    if (threadIdx.x < 64) {
        int l = threadIdx.x;
        u32 s0 = h[2 * l], s1 = h[2 * l + 1];
        u32 ps = s0 + s1;
        u32 x = ps;
        for (int d = 1; d < 64; d <<= 1) {
            u32 y = __shfl_up(x, (unsigned)d);
            if (l >= d) x += y;
        }
        u32 ex = x - ps;  // exclusive pair prefix within bucket
        ks[2 * l] = ex;
        ks[2 * l + 1] = ex + s0;
        int gk = b * 128 + 2 * l;
        if (gk < NCNT) rowinfo[gk] = make_uint2(gstart + ex, s0);
        if (gk + 1 < NCNT) rowinfo[gk + 1] = make_uint2(gstart + ex + s0, s1);
    }
    __syncthreads();
    for (int i = threadIdx.x; i < size; i += 256) {
        u32 en = stage[gstart + i];
        u32 kl = en >> 17;
        u32 p = atomicAdd(&ks[kl], 1u);
        csr[gstart + p] = en & 0x1FFFFu;
    }
}

// ---------------- 8-wide branchless gather body (r6, unchanged) ------------
#define GATHER8(SRC)                                                          \
    for (u32 base = 0; base < deg; base += 64) {                              \
        int m = (int)min(64u, deg - base);                                    \
        int myidx = (lane < m) ? (int)csr[start + base + lane] : 0;           \
        for (int t = 0; t < m; t += 8) {                                      \
            int i1 = min(t + 1, m - 1), i2 = min(t + 2, m - 1);               \
            int i3 = min(t + 3, m - 1), i4 = min(t + 4, m - 1);               \
            int i5 = min(t + 5, m - 1), i6 = min(t + 6, m - 1);               \
            int i7 = min(t + 7, m - 1);                                       \
            int r0 = __shfl(myidx, t),  r1 = __shfl(myidx, i1);               \
            int r2 = __shfl(myidx, i2), r3 = __shfl(myidx, i3);               \
            int r4 = __shfl(myidx, i4), r5 = __shfl(myidx, i5);               \
            int r6 = __shfl(myidx, i6), r7 = __shfl(myidx, i7);               \
            u32 u0 = ((const u32*)(SRC + (size_t)r0 * C))[lane];              \
            u32 u1 = ((const u32*)(SRC + (size_t)r1 * C))[lane];              \
            u32 u2 = ((const u32*)(SRC + (size_t)r2 * C))[lane];              \
            u32 u3 = ((const u32*)(SRC + (size_t)r3 * C))[lane];              \
            u32 u4 = ((const u32*)(SRC + (size_t)r4 * C))[lane];              \
            u32 u5 = ((const u32*)(SRC + (size_t)r5 * C))[lane];              \
            u32 u6 = ((const u32*)(SRC + (size_t)r6 * C))[lane];              \
            u32 u7 = ((const u32*)(SRC + (size_t)r7 * C))[lane];              \
            float k1 = (t + 1 < m) ? 1.f : 0.f, k2 = (t + 2 < m) ? 1.f : 0.f; \
            float k3 = (t + 3 < m) ? 1.f : 0.f, k4 = (t + 4 < m) ? 1.f : 0.f; \
            float k5 = (t + 5 < m) ? 1.f : 0.f, k6 = (t + 6 < m) ? 1.f : 0.f; \
            float k7 = (t + 7 < m) ? 1.f : 0.f;                               \
            ax += bf2f((u16)(u0 & 0xffffu)) + k1 * bf2f((u16)(u1 & 0xffffu))  \
                + k2 * bf2f((u16)(u2 & 0xffffu)) + k3 * bf2f((u16)(u3 & 0xffffu)) \
                + k4 * bf2f((u16)(u4 & 0xffffu)) + k5 * bf2f((u16)(u5 & 0xffffu)) \
                + k6 * bf2f((u16)(u6 & 0xffffu)) + k7 * bf2f((u16)(u7 & 0xffffu)); \
            ay += bf2f((u16)(u0 >> 16)) + k1 * bf2f((u16)(u1 >> 16))          \
                + k2 * bf2f((u16)(u2 >> 16)) + k3 * bf2f((u16)(u3 >> 16))     \
                + k4 * bf2f((u16)(u4 >> 16)) + k5 * bf2f((u16)(u5 >> 16))     \
                + k6 * bf2f((u16)(u6 >> 16)) + k7 * bf2f((u16)(u7 >> 16));    \
        }                                                                     \
    }

// ---------------- edge gather over CSR: 1 edge per wave -------------------
__global__ __launch_bounds__(256) void edge_gather_k(const u16* __restrict__ xw,
                                                     const uint2* __restrict__ rowinfo,
                                                     const u32* __restrict__ csrC,
                                                     u16* __restrict__ ef) {
    int e = blockIdx.x * 4 + (threadIdx.x >> 6);
    if (e >= N_EDGES) return;
    int lane = threadIdx.x & 63;
    uint2 ri = rowinfo[e];
    u32 deg = ri.y;
    u32 start = ri.x;  // absolute position in combined csr
    const u32* csr = csrC;
    float ax = 0.f, ay = 0.f;
    GATHER8(xw)
    float sc = deg ? 1.f / (float)deg : 0.f;
    ((u32*)(ef + (size_t)e * C))[lane] =
        (u32)f2bf(ax * sc) | ((u32)f2bf(ay * sc) << 16);
}

// ---------------- node gather over CSR: 1 node per wave -------------------
__global__ __launch_bounds__(256) void node_gather_k(const u16* __restrict__ ef,
                                                     const uint2* __restrict__ rowinfo,
                                                     const u32* __restrict__ csrC,
                                                     const float* __restrict__ bias,
                                                     float* __restrict__ out) {
    int v = blockIdx.x * 4 + (threadIdx.x >> 6);
    if (v >= N_NODES) return;
    int lane = threadIdx.x & 63;
    uint2 ri = rowinfo[N_EDGES + v];
    u32 deg = ri.y;
    u32 start = ri.x;  // absolute position in combined csr
    const u32* csr = csrC;
    float ax = 0.f, ay = 0.f;
    GATHER8(ef)
    float b0 = bias[2 * lane], b1 = bias[2 * lane + 1];
    float sc = deg ? 1.f / (float)deg : 0.f;
    float2 r;
    r.x = ax * sc + b0;
    r.y = ay * sc + b1;
    ((float2*)(out + (size_t)v * C))[lane] = r;
}

extern "C" void kernel_launch(void* const* d_in, const int* in_sizes, int n_in,
                              void* d_out, int out_size, void* d_ws, size_t ws_size,
                              hipStream_t stream) {
    const float* x = (const float*)d_in[0];     // [N_NODES,128] f32
    const int* node_idx = (const int*)d_in[1];  // [2, NNZ] row-major int32
    const int nnz = in_sizes[1] / 2;
    const int* edge_idx = node_idx + nnz;
    const float* W = (const float*)d_in[2];     // [128,128] f32
    const float* bias = (const float*)d_in[3];  // [128] f32
    float* out = (float*)d_out;                 // [N_NODES,128] f32

    int nb1 = (nnz + BCHUNK - 1) / BCHUNK;      // 245 bucketize blocks
    int scanN = NBUCKC * nb1;                   // 287140 count-matrix entries
    int scanBlocks = (scanN + 1023) / 1024;     // 281 (<= 512 for scan_b2)

    // workspace layout (~20.3 MB), all 16B-aligned:
    u16* Wt = (u16*)d_ws;                           // 32 KB
    u16* ef = Wt + 16384;                           // 12.8 MB
    u32* cntM = (u32*)(ef + (size_t)N_EDGES * C);   // scanN u32 (1.15 MB)
    u32* offM = cntM + scanN;                       // scanN u32 (1.15 MB)
    u32* bsum2 = offM + scanN;                      // 512 u32
    uint2* rowinfo = (uint2*)(bsum2 + 512);         // 150000 uint2 (1.2 MB)
    u32* csrC = (u32*)(rowinfo + NCNT);             // 2*nnz u32 (4 MB)

    // d_out (51.2 MB f32) doubles as scratch:
    //   [0, 25.6 MB):    xw bf16        — consumed by edge_gather
    //   [25.6, 29.6 MB): stage (packed) — consumed by bucket_csr_k
    // node_gather then overwrites the whole buffer with the f32 output.
    u16* xw = (u16*)d_out;
    u32* stage = (u32*)((char*)d_out + (size_t)N_NODES * C * 2);

    transpose_w<<<64, 256, 0, stream>>>(W, Wt);
    gemm_k<<<G_GEMM, 256, 0, stream>>>(x, Wt, xw);
    bucket_hist_k<<<nb1, 256, 0, stream>>>(node_idx, edge_idx, cntM, nnz, nb1);
    scan_a2<<<scanBlocks, 256, 0, stream>>>(cntM, offM, bsum2, scanN);
    scan_b2<<<1, 256, 0, stream>>>(bsum2, scanBlocks);
    bucket_place_k<<<nb1, 256, 0, stream>>>(node_idx, edge_idx, offM, bsum2,
                                            stage, nnz, nb1);
    bucket_csr_k<<<NBUCKC, 256, 0, stream>>>(offM, bsum2, stage, csrC, rowinfo,
                                             nnz, nb1);
    // 1 edge/node per wave, 4 waves per block
    edge_gather_k<<<(N_EDGES + 3) / 4, 256, 0, stream>>>(xw, rowinfo, csrC, ef);
    node_gather_k<<<(N_NODES + 3) / 4, 256, 0, stream>>>(ef, rowinfo, csrC, bias, out);
}